// Round 1
// baseline (296.733 us; speedup 1.0000x reference)
//
#include <hip/hip_runtime.h>

// Problem constants
#define BB   4
#define NN   30000
#define TT   12
#define EE   240000
#define FT   24        // F_IN * T contiguous floats per (b, node)
#define BFT  96        // BB * FT values per edge

// Workspace layout (floats):
//   deg  : [0, NN)
//   nrm  : [NN, NN+EE)
//   eff  : [NN+EE, NN+EE+256)   (Wz0[32] Wz1[32] bz[32] Wh0[32] Wh1[32] bh[32] probs[12])
//   agg  : [NN+EE+256, ... + BB*NN*FT)
#define WS_DEG 0
#define WS_NRM (NN)
#define WS_EFF (NN + EE)
#define WS_AGG (NN + EE + 256)

// ---- tiny weight-folding kernel: 1 block ----------------------------------
__global__ void k_prep(const float* __restrict__ czw, const float* __restrict__ czb,
                       const float* __restrict__ lzw, const float* __restrict__ lzb,
                       const float* __restrict__ chw, const float* __restrict__ chb,
                       const float* __restrict__ lhw, const float* __restrict__ lhb,
                       const float* __restrict__ att, float* __restrict__ eff) {
    int j = threadIdx.x;
    if (j < 32) {
        float wz0 = 0.f, wz1 = 0.f, bz = 0.f, wh0 = 0.f, wh1 = 0.f, bh = 0.f;
        for (int k = 0; k < 32; ++k) {
            float lz = lzw[k * 32 + j], lh = lhw[k * 32 + j];
            wz0 = fmaf(czw[k],      lz, wz0);
            wz1 = fmaf(czw[32 + k], lz, wz1);
            bz  = fmaf(czb[k],      lz, bz);
            wh0 = fmaf(chw[k],      lh, wh0);
            wh1 = fmaf(chw[32 + k], lh, wh1);
            bh  = fmaf(chb[k],      lh, bh);
        }
        eff[j]        = wz0;
        eff[32 + j]   = wz1;
        eff[64 + j]   = bz + lzb[j];
        eff[96 + j]   = wh0;
        eff[128 + j]  = wh1;
        eff[160 + j]  = bh + lhb[j];
    } else if (j == 32) {
        // softmax over the 12 attention logits
        float m = -1e30f;
        for (int t = 0; t < TT; ++t) m = fmaxf(m, att[t]);
        float p[TT], s = 0.f;
        for (int t = 0; t < TT; ++t) { p[t] = __expf(att[t] - m); s += p[t]; }
        float inv = 1.0f / s;
        for (int t = 0; t < TT; ++t) eff[192 + t] = p[t] * inv;
    }
}

// ---- degree: init to 1 (self loops), then count dst -----------------------
__global__ void k_init_deg(float* __restrict__ deg) {
    int i = blockIdx.x * blockDim.x + threadIdx.x;
    if (i < NN) deg[i] = 1.0f;
}

__global__ void k_count(const int* __restrict__ dst, float* __restrict__ deg) {
    int e = blockIdx.x * blockDim.x + threadIdx.x;
    if (e < EE) atomicAdd(&deg[dst[e]], 1.0f);
}

__global__ void k_norm(const int* __restrict__ src, const int* __restrict__ dst,
                       const float* __restrict__ deg, float* __restrict__ nrm) {
    int e = blockIdx.x * blockDim.x + threadIdx.x;
    if (e < EE) nrm[e] = rsqrtf(deg[src[e]]) * rsqrtf(deg[dst[e]]);
}

// ---- agg init with self-loop contribution: agg = x * dinv^2 ---------------
__global__ void k_init_agg(const float* __restrict__ x, const float* __restrict__ deg,
                           float* __restrict__ agg) {
    int idx = blockIdx.x * blockDim.x + threadIdx.x;   // over BB*NN*FT
    if (idx < BB * NN * FT) {
        int n = (idx / FT) % NN;
        float di = rsqrtf(deg[n]);
        agg[idx] = x[idx] * (di * di);
    }
}

// ---- edge scatter: agg[b,dst,ft] += norm * x[b,src,ft] --------------------
__global__ void k_scatter(const float* __restrict__ x, const int* __restrict__ src,
                          const int* __restrict__ dst, const float* __restrict__ nrm,
                          float* __restrict__ agg) {
    long long tid = (long long)blockIdx.x * blockDim.x + threadIdx.x;  // over EE*BFT
    if (tid >= (long long)EE * BFT) return;
    int e  = (int)(tid / BFT);
    int k  = (int)(tid % BFT);
    int b  = k / FT;
    int ft = k % FT;
    int s = src[e], d = dst[e];
    float w = nrm[e];
    float v = w * x[(b * NN + s) * FT + ft];
    atomicAdd(&agg[(b * NN + d) * FT + ft], v);
}

// ---- per-node combine: gates + attention sum + head -----------------------
__global__ void __launch_bounds__(256)
k_node(const float* __restrict__ agg, const float* __restrict__ eff,
       const float* __restrict__ hw, const float* __restrict__ hb,
       float* __restrict__ out) {
    __shared__ float s[608];   // eff[204] | head_w[384] | head_b[12]
    int lt = threadIdx.x;
    for (int i = lt; i < 204; i += 256) s[i] = eff[i];
    for (int i = lt; i < 384; i += 256) s[204 + i] = hw[i];
    if (lt < 12) s[588 + lt] = hb[lt];
    __syncthreads();

    int tid = blockIdx.x * 256 + lt;   // over BB*NN
    if (tid >= BB * NN) return;

    // vectorized load of this node's 24 aggregated features
    float4 buf[6];
    const float4* a4 = reinterpret_cast<const float4*>(agg + (long long)tid * FT);
#pragma unroll
    for (int i = 0; i < 6; ++i) buf[i] = a4[i];
    const float* av = reinterpret_cast<const float*>(buf);  // av[f*12 + t]

    float acc[32];
#pragma unroll
    for (int j = 0; j < 32; ++j) acc[j] = 0.f;

#pragma unroll
    for (int t = 0; t < TT; ++t) {
        float v0 = av[t], v1 = av[12 + t], p = s[192 + t];
#pragma unroll
        for (int j = 0; j < 32; ++j) {
            float zp = fmaf(v1, s[32 + j],  fmaf(v0, s[j],      s[64 + j]));
            float hp = fmaf(v1, s[128 + j], fmaf(v0, s[96 + j], s[160 + j]));
            float z  = 1.0f / (1.0f + __expf(-zp));               // sigmoid (overflow-safe)
            hp = fminf(fmaxf(hp, -15.0f), 15.0f);                 // tanh saturation guard
            float e2 = __expf(2.0f * hp);
            float h  = (e2 - 1.0f) / (e2 + 1.0f);
            acc[j] = fmaf(p * (1.0f - z), h, acc[j]);
        }
    }

#pragma unroll
    for (int j = 0; j < 32; ++j) acc[j] = fmaxf(acc[j], 0.f);  // relu

    float* o = out + (long long)tid * 12;
#pragma unroll
    for (int k = 0; k < 12; ++k) {
        float r = s[588 + k];
#pragma unroll
        for (int j = 0; j < 32; ++j) r = fmaf(acc[j], s[204 + j * 12 + k], r);
        o[k] = r;
    }
}

extern "C" void kernel_launch(void* const* d_in, const int* in_sizes, int n_in,
                              void* d_out, int out_size, void* d_ws, size_t ws_size,
                              hipStream_t stream) {
    const float* x   = (const float*)d_in[0];
    const int*   ei  = (const int*)d_in[1];     // (2,E): [0,E)=src, [E,2E)=dst
    const float* att = (const float*)d_in[2];
    const float* czw = (const float*)d_in[3];
    const float* czb = (const float*)d_in[4];
    const float* lzw = (const float*)d_in[5];
    const float* lzb = (const float*)d_in[6];
    // d_in[7..10] (conv_r / lin_r) are dead: H0 == 0 so H0*R == 0
    const float* chw = (const float*)d_in[11];
    const float* chb = (const float*)d_in[12];
    const float* lhw = (const float*)d_in[13];
    const float* lhb = (const float*)d_in[14];
    const float* hw  = (const float*)d_in[15];
    const float* hb  = (const float*)d_in[16];
    float* out = (float*)d_out;

    float* ws  = (float*)d_ws;
    float* deg = ws + WS_DEG;
    float* nrm = ws + WS_NRM;
    float* eff = ws + WS_EFF;
    float* agg = ws + WS_AGG;

    const int* src = ei;
    const int* dst = ei + EE;

    k_prep<<<1, 64, 0, stream>>>(czw, czb, lzw, lzb, chw, chb, lhw, lhb, att, eff);
    k_init_deg<<<(NN + 255) / 256, 256, 0, stream>>>(deg);
    k_count<<<(EE + 255) / 256, 256, 0, stream>>>(dst, deg);
    k_norm<<<(EE + 255) / 256, 256, 0, stream>>>(src, dst, deg, nrm);
    k_init_agg<<<(BB * NN * FT + 255) / 256, 256, 0, stream>>>(x, deg, agg);
    long long scatter_threads = (long long)EE * BFT;   // 23,040,000
    k_scatter<<<(int)((scatter_threads + 255) / 256), 256, 0, stream>>>(x, src, dst, nrm, agg);
    k_node<<<(BB * NN + 255) / 256, 256, 0, stream>>>(agg, eff, hw, hb, out);
}